// Round 7
// baseline (100.459 us; speedup 1.0000x reference)
//
#include <hip/hip_runtime.h>
#include <math.h>

#define POOL 7
#define FH 50
#define FW 50
#define FC 1024
#define FC4 (FC / 4)      // 256 vf4 per spatial cell
#define CHUNKS 4          // channel chunks; 64 vf4 (256 ch) per chunk
#define F4C 64            // vf4 per cell per chunk (one wave-wide load)
#define PH2 (FH / 2)      // 25
#define PW2 (FW / 2)      // 25

// Pyramid layout in d_ws (vf4 units, each cell = FC4 vf4):
//   Pw [FH][PW2]  : max over col-pairs   (1250 cells)
//   Ph [PH2][FW]  : max over row-pairs   (1250 cells)
//   P2 [PH2][PW2] : max over 2x2 blocks  ( 625 cells)
#define PW_OFF ((size_t)0)
#define PH_OFF ((size_t)1250 * FC4)
#define P2_OFF ((size_t)2500 * FC4)
#define WS_VF4 ((size_t)3125 * FC4)          // 12.8 MB total

typedef float vf4 __attribute__((ext_vector_type(4)));

static __device__ __forceinline__ vf4 vmax4(vf4 a, vf4 b) {
    vf4 r;
    r.x = fmaxf(a.x, b.x);
    r.y = fmaxf(a.y, b.y);
    r.z = fmaxf(a.z, b.z);
    r.w = fmaxf(a.w, b.w);
    return r;
}

// ---------------- bin-bounds helper (shared, bit-exact vs reference) -------
static __device__ __forceinline__ void roi_bounds(
    const float4 roi, int i, int j,
    int& r0, int& r1, int& c0, int& c1)
{
    const int h0 = (int)((float)FH * roi.x);
    const int w0 = (int)((float)FW * roi.y);
    const int h1 = (int)((float)FH * roi.z);
    const int w1 = (int)((float)FW * roi.w);
    const int rh = h1 - h0;
    const int rw = w1 - w0;
    const int hstep = rh / POOL;
    const int wstep = rw / POOL;

    int sh = i * hstep;
    int eh = (i < POOL - 1) ? (i + 1) * hstep : rh;
    if (sh == eh) { if (eh < rh) eh += 1; else sh -= 1; }
    int sw = j * wstep;
    int ew = (j < POOL - 1) ? (j + 1) * wstep : rw;
    if (sw == ew) { if (ew < rw) ew += 1; else sw -= 1; }

    r0 = max(0, h0 + sh);
    r1 = min(FH, h0 + eh);
    c0 = max(0, w0 + sw);
    c1 = min(FW, w0 + ew);
}

// ---------------- kernel 1: build 2x2 max pyramid --------------------------
// One wave per (2x2 spatial block, chunk). chunk = b&3 (XCD round-robin b%8
// pins each XCD to one channel chunk).
__global__ __launch_bounds__(256) void build_kernel(
    const float* __restrict__ fm, float* __restrict__ ws)
{
    const int b     = blockIdx.x;
    const int chunk = b & (CHUNKS - 1);
    const int wave  = threadIdx.x >> 6;
    const int lane  = threadIdx.x & 63;
    const int s     = (b >> 2) * 4 + wave;       // spatial 2x2 block id
    if (s >= PH2 * PW2) return;
    const int rr = s / PW2;
    const int cc = s - rr * PW2;
    const int f4 = chunk * F4C + lane;

    const vf4* fm4 = reinterpret_cast<const vf4*>(fm);
    const size_t rs = (size_t)FW * FC4;
    const vf4* p = fm4 + (size_t)(2 * rr) * rs + (size_t)(2 * cc) * FC4 + f4;

    vf4 a = p[0];
    vf4 bb = p[FC4];
    vf4 c = p[rs];
    vf4 d = p[rs + FC4];

    vf4 ab = vmax4(a, bb);     // row 2rr  col-pair
    vf4 cd = vmax4(c, d);      // row 2rr+1 col-pair
    vf4 ac = vmax4(a, c);      // col 2cc  row-pair
    vf4 bd = vmax4(bb, d);     // col 2cc+1 row-pair

    vf4* w4 = reinterpret_cast<vf4*>(ws);
    w4[PW_OFF + ((size_t)(2 * rr) * PW2 + cc) * FC4 + f4]     = ab;
    w4[PW_OFF + ((size_t)(2 * rr + 1) * PW2 + cc) * FC4 + f4] = cd;
    w4[PH_OFF + ((size_t)rr * FW + 2 * cc) * FC4 + f4]        = ac;
    w4[PH_OFF + ((size_t)rr * FW + 2 * cc + 1) * FC4 + f4]    = bd;
    w4[P2_OFF + ((size_t)rr * PW2 + cc) * FC4 + f4]           = vmax4(ab, cd);
}

// ---------------- kernel 2: pooled lookup via pyramid ----------------------
// One wave per (roi,bin,chunk). Bin range decomposes into aligned pairs
// (served by P2/Ph/Pw) + <=2 edge rows/cols (served by fm). ~2.4x fewer
// loads than reading every cell.
__global__ __launch_bounds__(256) void pool_kernel(
    const float* __restrict__ fm,
    const float* __restrict__ rois,
    const float* __restrict__ ws,
    float* __restrict__ out,
    int nbins)
{
    const int b     = blockIdx.x;
    const int chunk = b & (CHUNKS - 1);
    const int wave  = threadIdx.x >> 6;
    const int lane  = threadIdx.x & 63;
    const int gid   = (b >> 2) * 4 + wave;
    if (gid >= nbins) return;

    const int n  = gid / 49;
    const int ij = gid - n * 49;
    const int i  = ij / 7;
    const int j  = ij - i * 7;

    const float4 roi = reinterpret_cast<const float4*>(rois)[n];
    int r0, r1, c0, c1;
    roi_bounds(roi, i, j, r0, r1, c0, c1);

    // decompose rows: aligned pairs [rA,rB) + edge rows
    int rA = r0 + (r0 & 1);
    int rB = r1 & ~1;
    int eR[2]; int nER = 0;
    if (rA < rB) {
        if (r0 < rA) eR[nER++] = r0;
        if (rB < r1) eR[nER++] = rB;
    } else {
        for (int r = r0; r < r1; ++r) eR[nER++] = r;  // <=2 rows
        rA = 0; rB = 0;
    }
    // decompose cols
    int cA = c0 + (c0 & 1);
    int cB = c1 & ~1;
    int eC[2]; int nEC = 0;
    if (cA < cB) {
        if (c0 < cA) eC[nEC++] = c0;
        if (cB < c1) eC[nEC++] = cB;
    } else {
        for (int c = c0; c < c1; ++c) eC[nEC++] = c;  // <=2 cols
        cA = 0; cB = 0;
    }

    const int f4 = chunk * F4C + lane;
    vf4 acc = {-INFINITY, -INFINITY, -INFINITY, -INFINITY};

    const vf4* w4     = reinterpret_cast<const vf4*>(ws);
    const vf4* p2base = w4 + P2_OFF + f4;
    const vf4* phbase = w4 + PH_OFF + f4;
    const vf4* pwbase = w4 + PW_OFF + f4;
    const vf4* fmbase = reinterpret_cast<const vf4*>(fm) + f4;

    // interior: pair-rows x pair-cols from P2
    for (int rp = rA; rp < rB; rp += 2) {
        const vf4* row = p2base + (size_t)(rp >> 1) * PW2 * FC4;
        int cp = cA;
        for (; cp + 2 < cB; cp += 4) {
            vf4 x = row[(size_t)(cp >> 1) * FC4];
            vf4 y = row[(size_t)((cp >> 1) + 1) * FC4];
            acc = vmax4(acc, vmax4(x, y));
        }
        if (cp < cB) acc = vmax4(acc, row[(size_t)(cp >> 1) * FC4]);
    }
    // pair-rows x edge-cols from Ph
    for (int rp = rA; rp < rB; rp += 2) {
        const vf4* row = phbase + (size_t)(rp >> 1) * FW * FC4;
        for (int k = 0; k < nEC; ++k)
            acc = vmax4(acc, row[(size_t)eC[k] * FC4]);
    }
    // edge-rows x pair-cols from Pw
    for (int k = 0; k < nER; ++k) {
        const vf4* row = pwbase + (size_t)eR[k] * PW2 * FC4;
        for (int cp = cA; cp < cB; cp += 2)
            acc = vmax4(acc, row[(size_t)(cp >> 1) * FC4]);
    }
    // edge-rows x edge-cols from fm
    for (int k = 0; k < nER; ++k) {
        const vf4* row = fmbase + (size_t)eR[k] * FW * FC4;
        for (int m = 0; m < nEC; ++m)
            acc = vmax4(acc, row[(size_t)eC[m] * FC4]);
    }

    vf4* o = reinterpret_cast<vf4*>(out) + (size_t)gid * FC4 + f4;
    __builtin_nontemporal_store(acc, o);
}

// ---------------- fallback (R6 path) if ws too small -----------------------
__global__ __launch_bounds__(256) void roipool_direct_kernel(
    const float* __restrict__ fm,
    const float* __restrict__ rois,
    float* __restrict__ out,
    int nbins)
{
    const int b     = blockIdx.x;
    const int chunk = b & (CHUNKS - 1);
    const int wave  = threadIdx.x >> 6;
    const int lane  = threadIdx.x & 63;
    const int gid   = (b >> 2) * 4 + wave;
    if (gid >= nbins) return;

    const int n  = gid / 49;
    const int ij = gid - n * 49;
    const int i  = ij / 7;
    const int j  = ij - i * 7;

    const float4 roi = reinterpret_cast<const float4*>(rois)[n];
    int r0, r1, c0, c1;
    roi_bounds(roi, i, j, r0, r1, c0, c1);

    const int f4 = chunk * F4C + lane;
    vf4 acc = {-INFINITY, -INFINITY, -INFINITY, -INFINITY};
    const vf4* fm4 = reinterpret_cast<const vf4*>(fm);
    const size_t rowstride = (size_t)FW * FC4;

    for (int r = r0; r < r1; ++r) {
        const vf4* rp0 = fm4 + (size_t)r * rowstride + f4;
        int c = c0;
        for (; c + 1 < c1; c += 2) {
            vf4 a0 = rp0[(size_t)c * FC4];
            vf4 a1 = rp0[(size_t)(c + 1) * FC4];
            acc = vmax4(acc, vmax4(a0, a1));
        }
        if (c < c1) acc = vmax4(acc, rp0[(size_t)c * FC4]);
    }

    vf4* o = reinterpret_cast<vf4*>(out) + (size_t)gid * FC4 + f4;
    __builtin_nontemporal_store(acc, o);
}

extern "C" void kernel_launch(void* const* d_in, const int* in_sizes, int n_in,
                              void* d_out, int out_size, void* d_ws, size_t ws_size,
                              hipStream_t stream) {
    const float* features = (const float*)d_in[0];  // [1,50,50,1024]
    const float* rois     = (const float*)d_in[1];  // [N,4]
    float* out            = (float*)d_out;          // [N,7,7,1024]
    const int N = in_sizes[1] / 4;
    const int nbins = N * POOL * POOL;              // 14700

    const size_t ws_needed = WS_VF4 * sizeof(vf4);  // 12.8 MB

    if (ws_size >= ws_needed) {
        // kernel 1: pyramid (625 2x2 blocks x 4 chunks, 4 waves/block)
        const int nspatial = PH2 * PW2;             // 625
        dim3 bgrid(((nspatial + 3) / 4) * CHUNKS);  // 628
        build_kernel<<<bgrid, dim3(256), 0, stream>>>(features, (float*)d_ws);
        // kernel 2: pooled lookup
        dim3 pgrid(((nbins + 3) / 4) * CHUNKS);
        pool_kernel<<<pgrid, dim3(256), 0, stream>>>(
            features, rois, (const float*)d_ws, out, nbins);
    } else {
        dim3 grid(((nbins + 3) / 4) * CHUNKS);
        roipool_direct_kernel<<<grid, dim3(256), 0, stream>>>(
            features, rois, out, nbins);
    }
}